// Round 6
// baseline (1339.927 us; speedup 1.0000x reference)
//
#include <hip/hip_runtime.h>
#include <cmath>

#define VOCAB 32000
#define EMB   256
#define HID   512
#define TLEN  513      // SEQ + 1
#define G4    2048     // 4*HID
#define NWG   32       // recurrence roles
#define GRID_LSTM 256  // launched WGs; >=1 bucket gets >=32 (pigeonhole)
#define SOS   1

typedef unsigned long long u64;
typedef unsigned int uivec4 __attribute__((ext_vector_type(4)));
typedef float f32x4 __attribute__((ext_vector_type(4)));

__device__ inline float fsig(float x)  { return __builtin_amdgcn_rcpf(1.f + __expf(-x)); }
__device__ inline float ftanh(float x) { return 1.f - 2.f * __builtin_amdgcn_rcpf(__expf(2.f * x) + 1.f); }
__device__ inline float fma4(f32x4 w, f32x4 h, float a) {
    return fmaf(w[0], h[0], fmaf(w[1], h[1], fmaf(w[2], h[2], fmaf(w[3], h[3], a))));
}

// ---------------------------------------------------------------------------
// Kernel A: Xg[t][r] = W_ih[r] . emb[tok_t] + b_ih[r] + b_hh[r]   (proven)
// ---------------------------------------------------------------------------
__global__ __launch_bounds__(256) void precompute_gates(
    const int* __restrict__ seq, const float* __restrict__ emb,
    const float* __restrict__ W_ih, const float* __restrict__ b_ih,
    const float* __restrict__ b_hh, float* __restrict__ Xg)
{
    __shared__ __align__(16) float ebuf[16][EMB];
    const int bt = blockIdx.x;   // 0..32
    const int br = blockIdx.y;   // 0..7
    const int tid = threadIdx.x;

    for (int tt = 0; tt < 16; ++tt) {
        int t = bt * 16 + tt;
        if (t < TLEN) {
            int tok = (t == 0) ? SOS : seq[t - 1];
            ebuf[tt][tid] = emb[(size_t)tok * EMB + tid];
        }
    }
    __syncthreads();

    const int row = br * 256 + tid;
    float acc[16];
#pragma unroll
    for (int tt = 0; tt < 16; ++tt) acc[tt] = 0.f;

    const float4* wp = (const float4*)(W_ih + (size_t)row * EMB);
#pragma unroll 4
    for (int k4 = 0; k4 < EMB / 4; ++k4) {
        float4 w = wp[k4];
#pragma unroll
        for (int tt = 0; tt < 16; ++tt) {
            float4 e = *(const float4*)&ebuf[tt][k4 * 4];
            acc[tt] = fmaf(w.x, e.x, fmaf(w.y, e.y, fmaf(w.z, e.z, fmaf(w.w, e.w, acc[tt]))));
        }
    }

    const float bias = b_ih[row] + b_hh[row];
    for (int tt = 0; tt < 16; ++tt) {
        int t = bt * 16 + tt;
        if (t < TLEN) Xg[(size_t)t * G4 + row] = acc[tt] + bias;
    }
}

// ---------------------------------------------------------------------------
// Kernel B: persistent LSTM recurrence.
// 256 WGs x 512 threads. Slots claimed per-XCC bucket; winner = first bucket
// with >=32 claimants (exists by pigeonhole); its slots 0..31 survive, rest
// exit. Survivors likely share one XCD L2 -> sc0 fast transport (bounded K,
// sticky-disabled at t==2 if the probe fails). Guaranteed-progress MALL pk
// protocol (proven rounds 2/5) underneath. W_hh rows held in 16 named f32x4
// registers, pinned with asm so the compiler cannot rematerialize the loads.
// ---------------------------------------------------------------------------
__global__ __launch_bounds__(512, 2) void lstm_recurrence(
    const float* __restrict__ Xg, const float* __restrict__ W_hh,
    const float* __restrict__ h0, const float* __restrict__ c0,
    float* __restrict__ hs, u64* pk, u64* pf, int* ctrs,
    float* __restrict__ out_hT, float* __restrict__ out_cT)
{
    __shared__ __align__(16) float hbuf[HID];
    __shared__ float pbuf[512];
    __shared__ int s_slot, s_go, s_usefast;

    const int tid = threadIdx.x;

    // ---- claim + arrival + winner (tid 0) ----
    if (tid == 0) {
        unsigned xcc = 0;
        asm volatile("s_getreg_b32 %0, hwreg(20, 0, 32)" : "=s"(xcc)); // HW_REG_XCC_ID
        xcc &= 7u;
        int slot = __hip_atomic_fetch_add(&ctrs[2 + xcc], 1,
                                          __ATOMIC_RELAXED, __HIP_MEMORY_SCOPE_AGENT);
        __hip_atomic_fetch_add(&ctrs[0], 1, __ATOMIC_RELEASE, __HIP_MEMORY_SCOPE_AGENT);
        s_slot = slot;
        s_go = 0;
        if (slot < NWG) {
            // terminates: every launched WG increments ctrs[0] before any wait,
            // and all 256 WGs (1024 waves) are co-resident on 256 CUs.
            while (__hip_atomic_load(&ctrs[0], __ATOMIC_ACQUIRE, __HIP_MEMORY_SCOPE_AGENT) < GRID_LSTM)
                __builtin_amdgcn_s_sleep(4);
            int winner = -1;
            for (int x = 0; x < 8; ++x) {
                int cx = __hip_atomic_load(&ctrs[2 + x], __ATOMIC_ACQUIRE, __HIP_MEMORY_SCOPE_AGENT);
                if (cx >= NWG) { winner = x; break; }
            }
            s_go = (winner == (int)xcc) ? 1 : 0;
        }
        s_usefast = 1;
    }
    __syncthreads();
    if (s_slot >= NWG || s_go != 1) return;
    const int wg = s_slot;

    // graph-replay safety: drop any stale L1/L2 lines before first pf access
    __builtin_amdgcn_fence(__ATOMIC_ACQUIRE, "agent");

    // ---- layout: 8 waves = 8 k-segments of 64 cols; lane: gate q, sub j ----
    const int seg = tid >> 6;       // 0..7
    const int ln  = tid & 63;
    const int q   = ln >> 4;        // gate i,f,g,o
    const int j   = ln & 15;
    const int row = q * HID + wg * 16 + j;

    const f32x4* wp4 = (const f32x4*)(W_hh + (size_t)row * HID + seg * 64);
    f32x4 w00 = wp4[0],  w01 = wp4[1],  w02 = wp4[2],  w03 = wp4[3];
    f32x4 w04 = wp4[4],  w05 = wp4[5],  w06 = wp4[6],  w07 = wp4[7];
    f32x4 w08 = wp4[8],  w09 = wp4[9],  w10 = wp4[10], w11 = wp4[11];
    f32x4 w12 = wp4[12], w13 = wp4[13], w14 = wp4[14], w15 = wp4[15];
    // pin: forbid rematerialization of the W_hh loads inside the t-loop
    asm volatile("" : "+v"(w00), "+v"(w01), "+v"(w02), "+v"(w03));
    asm volatile("" : "+v"(w04), "+v"(w05), "+v"(w06), "+v"(w07));
    asm volatile("" : "+v"(w08), "+v"(w09), "+v"(w10), "+v"(w11));
    asm volatile("" : "+v"(w12), "+v"(w13), "+v"(w14), "+v"(w15));

    float c = (tid < 16) ? c0[wg * 16 + tid] : 0.f;
    if (tid < HID) hbuf[tid] = h0[tid];
    __syncthreads();

    for (int t = 0; t < TLEN; ++t) {
        const bool uf = (s_usefast != 0);

        float xg0 = 0.f, xg1 = 0.f, xg2 = 0.f, xg3 = 0.f;
        if (tid < 16) {
            const float* xp = Xg + (size_t)t * G4 + wg * 16 + tid;
            xg0 = xp[0]; xg1 = xp[512]; xg2 = xp[1024]; xg3 = xp[1536];
        }

        if (t > 0) {
            bool fell = false;
            if (tid < 256) {
                const size_t off = (size_t)(t & 1) * HID + 2 * tid;
                u64 v0 = 0, v1 = 0;
                bool ok0 = false, ok1 = false;
                if (uf) {                               // bounded XCD-L2 phase
                    const int K = (t == 1) ? 32 : 8;
                    u64 fa = (u64)(uintptr_t)(pf + off);
                    for (int it = 0; it < K; ++it) {
                        uivec4 pr;
                        asm volatile("global_load_dwordx4 %0, %1, off sc0\n\t"
                                     "s_waitcnt vmcnt(0)" : "=v"(pr) : "v"(fa));
                        if (!ok0 && pr.y == (unsigned)t) { v0 = ((u64)pr.y << 32) | pr.x; ok0 = true; }
                        if (!ok1 && pr.w == (unsigned)t) { v1 = ((u64)pr.w << 32) | pr.z; ok1 = true; }
                        if (ok0 && ok1) break;
                    }
                    fell = !(ok0 && ok1);
                }
                if (!(ok0 && ok1)) {                    // guaranteed MALL path
                    u64 sa = (u64)(uintptr_t)(pk + off);
                    do {
                        uivec4 pr;
                        asm volatile("global_load_dwordx4 %0, %1, off sc0 sc1\n\t"
                                     "s_waitcnt vmcnt(0)" : "=v"(pr) : "v"(sa));
                        if (!ok0 && pr.y == (unsigned)t) { v0 = ((u64)pr.y << 32) | pr.x; ok0 = true; }
                        if (!ok1 && pr.w == (unsigned)t) { v1 = ((u64)pr.w << 32) | pr.z; ok1 = true; }
                    } while (!(ok0 && ok1));
                }
                hbuf[2 * tid]     = __uint_as_float((unsigned)v0);
                hbuf[2 * tid + 1] = __uint_as_float((unsigned)v1);
            }
            int nfail = __syncthreads_count(fell ? 1 : 0);   // B1
            if (t == 2 && tid == 0 && nfail > 0) s_usefast = 0;  // sticky probe
        }

        // partial matvec over my 64-col segment (hbuf b128 reads are
        // wave-uniform broadcasts: conflict-free)
        const f32x4* hp = (const f32x4*)&hbuf[seg * 64];
        float a0 = 0.f, a1 = 0.f, a2 = 0.f, a3 = 0.f;
        a0 = fma4(w00, hp[0],  a0); a1 = fma4(w01, hp[1],  a1);
        a2 = fma4(w02, hp[2],  a2); a3 = fma4(w03, hp[3],  a3);
        a0 = fma4(w04, hp[4],  a0); a1 = fma4(w05, hp[5],  a1);
        a2 = fma4(w06, hp[6],  a2); a3 = fma4(w07, hp[7],  a3);
        a0 = fma4(w08, hp[8],  a0); a1 = fma4(w09, hp[9],  a1);
        a2 = fma4(w10, hp[10], a2); a3 = fma4(w11, hp[11], a3);
        a0 = fma4(w12, hp[12], a0); a1 = fma4(w13, hp[13], a1);
        a2 = fma4(w14, hp[14], a2); a3 = fma4(w15, hp[15], a3);
        pbuf[tid] = (a0 + a1) + (a2 + a3);
        __syncthreads();                                 // B2

        if (tid < 16) {
            float gi = xg0, gf = xg1, gg = xg2, go = xg3;
#pragma unroll
            for (int s = 0; s < 8; ++s) {
                gi += pbuf[s * 64 + tid];
                gf += pbuf[s * 64 + 16 + tid];
                gg += pbuf[s * 64 + 32 + tid];
                go += pbuf[s * 64 + 48 + tid];
            }
            float i_ = fsig(gi);
            float f_ = fsig(gf);
            float g_ = ftanh(gg);
            float o_ = fsig(go);
            c = fmaf(f_, c, i_ * g_);
            float h_ = o_ * ftanh(c);
            hs[(size_t)t * HID + wg * 16 + tid] = h_;
            if (t < TLEN - 1) {
                u64 word = ((u64)(unsigned)(t + 1) << 32) | (u64)__float_as_uint(h_);
                size_t po = (size_t)((t + 1) & 1) * HID + wg * 16 + tid;
                u64 faddr = (u64)(uintptr_t)(pf + po);
                asm volatile("global_store_dwordx2 %0, %1, off sc0"
                             :: "v"(faddr), "v"(word) : "memory");
                __hip_atomic_store(&pk[po], word, __ATOMIC_RELAXED, __HIP_MEMORY_SCOPE_AGENT);
            } else {
                out_hT[wg * 16 + tid] = h_;
                out_cT[wg * 16 + tid] = c;
            }
        }
        // pbuf reads by act lanes complete before they reach next B1;
        // pbuf is rewritten only after next B1 -> 2 barriers/step suffice.
    }
}

// ---------------------------------------------------------------------------
// Kernel C: out[t][v] = hs[t] . W_out[v] + b_out[v]   (fp32, B^T input)
// 128x128 tile, BK=32, 8x8 register tile, 256 threads, grid (5, 250). Proven.
// ---------------------------------------------------------------------------
#define BM 128
#define BN 128
#define BK 32
#define LDT (BK + 4)   // 36: float4-aligned pad

__global__ __launch_bounds__(256) void out_gemm(
    const float* __restrict__ hs, const float* __restrict__ W_out,
    const float* __restrict__ b_out, float* __restrict__ out)
{
    __shared__ __align__(16) float As[BM][LDT];
    __shared__ __align__(16) float Bs[BN][LDT];

    const int tb = blockIdx.x;     // 0..4   (time tiles; fast dim)
    const int vb = blockIdx.y;     // 0..249 (vocab tiles)
    const int tid = threadIdx.x;
    const int tx = tid & 15;       // n group
    const int ty = tid >> 4;       // m group

    const int m0 = tb * BM, n0 = vb * BN;
    float acc[8][8];
#pragma unroll
    for (int i = 0; i < 8; ++i)
#pragma unroll
        for (int jj = 0; jj < 8; ++jj) acc[i][jj] = 0.f;

    for (int k0 = 0; k0 < HID; k0 += BK) {
#pragma unroll
        for (int it = 0; it < 4; ++it) {
            int li = tid + it * 256;        // 0..1023
            int m  = li >> 3;               // row 0..127
            int kq = li & 7;                // float4 index within BK
            int t  = m0 + m;
            float4 fa = (t < TLEN) ? *(const float4*)&hs[(size_t)t * HID + k0 + kq * 4]
                                   : make_float4(0.f, 0.f, 0.f, 0.f);
            *(float4*)&As[m][kq * 4] = fa;
            float4 fb = *(const float4*)&W_out[(size_t)(n0 + m) * HID + k0 + kq * 4];
            *(float4*)&Bs[m][kq * 4] = fb;
        }
        __syncthreads();

#pragma unroll
        for (int k4 = 0; k4 < BK / 4; ++k4) {
            float4 a4[8], b4[8];
#pragma unroll
            for (int i = 0; i < 8; ++i) a4[i] = *(const float4*)&As[ty + 16 * i][k4 * 4];
#pragma unroll
            for (int jj = 0; jj < 8; ++jj) b4[jj] = *(const float4*)&Bs[tx + 16 * jj][k4 * 4];
#pragma unroll
            for (int i = 0; i < 8; ++i)
#pragma unroll
                for (int jj = 0; jj < 8; ++jj) {
                    acc[i][jj] = fmaf(a4[i].x, b4[jj].x,
                                 fmaf(a4[i].y, b4[jj].y,
                                 fmaf(a4[i].z, b4[jj].z,
                                 fmaf(a4[i].w, b4[jj].w, acc[i][jj]))));
                }
        }
        __syncthreads();
    }

#pragma unroll
    for (int jj = 0; jj < 8; ++jj) {
        int v = n0 + tx + 16 * jj;
        float bo = b_out[v];
#pragma unroll
        for (int i = 0; i < 8; ++i) {
            int t = m0 + ty + 16 * i;
            if (t < TLEN) out[(size_t)t * VOCAB + v] = acc[i][jj] + bo;
        }
    }
}

// ---------------------------------------------------------------------------
extern "C" void kernel_launch(void* const* d_in, const int* in_sizes, int n_in,
                              void* d_out, int out_size, void* d_ws, size_t ws_size,
                              hipStream_t stream)
{
    const int*   seq   = (const int*)  d_in[0];
    const float* h0    = (const float*)d_in[1];
    const float* c0    = (const float*)d_in[2];
    const float* emb   = (const float*)d_in[3];
    const float* W_ih  = (const float*)d_in[4];
    const float* W_hh  = (const float*)d_in[5];
    const float* b_ih  = (const float*)d_in[6];
    const float* b_hh  = (const float*)d_in[7];
    const float* W_out = (const float*)d_in[8];
    const float* b_out = (const float*)d_in[9];

    float* out_logits = (float*)d_out;                      // [513][32000]
    float* out_hT     = out_logits + (size_t)TLEN * VOCAB;  // [512]
    float* out_cT     = out_hT + HID;                       // [512]

    float* Xg   = (float*)d_ws;                     // 513*2048 f
    float* hs   = Xg + (size_t)TLEN * G4;           // 513*512 f
    u64*   pk   = (u64*)(hs + (size_t)TLEN * HID);  // [2][512] MALL words
    u64*   pf   = pk + 2 * HID;                     // [2][512] XCD-L2 words
    int*   ctrs = (int*)(pf + 2 * HID);             // [16] claim counters

    size_t zbytes = (4 * HID) * sizeof(u64) + 16 * sizeof(int);
    hipMemsetAsync(pk, 0, zbytes, stream);
    precompute_gates<<<dim3(33, 8), 256, 0, stream>>>(seq, emb, W_ih, b_ih, b_hh, Xg);
    lstm_recurrence<<<GRID_LSTM, 512, 0, stream>>>(Xg, W_hh, h0, c0, hs, pk, pf, ctrs,
                                                   out_hT, out_cT);
    out_gemm<<<dim3(5, 250), 256, 0, stream>>>(hs, W_out, b_out, out_logits);
}